// Round 2
// baseline (1785.124 us; speedup 1.0000x reference)
//
#include <hip/hip_runtime.h>
#include <cmath>

typedef short short8 __attribute__((ext_vector_type(8)));
typedef float floatx4 __attribute__((ext_vector_type(4)));
typedef unsigned short ushortx4 __attribute__((ext_vector_type(4)));

__device__ inline float bf2f(unsigned short u) {
  return __uint_as_float(((unsigned)u) << 16);
}
__device__ inline unsigned short f2bf(float x) {
  unsigned u = __float_as_uint(x);
  u = (u + 0x7FFFu + ((u >> 16) & 1u)) >> 16;
  return (unsigned short)u;
}

// ---------------- dtype probe: bf16 vs fp32 inputs ----------------
__global__ void probe_kernel(const unsigned short* __restrict__ in, int* __restrict__ flag) {
  __shared__ float red[256];
  float m = 0.f;
  for (int i = threadIdx.x; i < 8192; i += 256) {
    float v = fabsf(bf2f(in[i]));
    if (!isnan(v)) m = fmaxf(m, v);
  }
  red[threadIdx.x] = m;
  __syncthreads();
  for (int s = 128; s > 0; s >>= 1) {
    if (threadIdx.x < s) red[threadIdx.x] = fmaxf(red[threadIdx.x], red[threadIdx.x + s]);
    __syncthreads();
  }
  if (threadIdx.x == 0) flag[0] = (red[0] < 1000.0f) ? 1 : 0;  // 1 = input is bf16
}

// ---------------- cast X -> bf16 (or copy), 8 elems/thread ----------------
__global__ __launch_bounds__(256) void cast_any(const void* __restrict__ in,
                                                unsigned short* __restrict__ out,
                                                const int* __restrict__ flag, int n) {
  int i = (blockIdx.x * 256 + threadIdx.x) * 8;
  if (i >= n) return;
  if (flag[0]) {
    *(uint4*)(out + i) = *(const uint4*)((const unsigned short*)in + i);
  } else {
    const float* f = (const float*)in + i;
    float4 a = *(const float4*)f;
    float4 b = *(const float4*)(f + 4);
    ushortx4 o0, o1;
    o0.x = f2bf(a.x); o0.y = f2bf(a.y); o0.z = f2bf(a.z); o0.w = f2bf(a.w);
    o1.x = f2bf(b.x); o1.y = f2bf(b.y); o1.z = f2bf(b.z); o1.w = f2bf(b.w);
    *(ushortx4*)(out + i) = o0;
    *(ushortx4*)(out + i + 4) = o1;
  }
}

// ---------------- transpose+cast W (K=4096 x N) -> WT[n][k] bf16, vectorized ----------------
__global__ __launch_bounds__(256) void transpose_cast(const void* __restrict__ W,
                                                      unsigned short* __restrict__ WT,
                                                      const int* __restrict__ flag,
                                                      int N, int rowOff) {
  __shared__ unsigned short tile[32][36];  // pad 4 -> 8B-aligned rows, mild 2-way conflicts only
  int n0 = blockIdx.x * 32, k0 = blockIdx.y * 32;
  bool isbf = flag[0] != 0;
  int tx = threadIdx.x & 7;   // n-quad / k-quad
  int ty = threadIdx.x >> 3;  // 0..31
  {
    int k = k0 + ty, nb = tx * 4;
    if (isbf) {
      ushortx4 u = *(const ushortx4*)((const unsigned short*)W + (size_t)k * N + n0 + nb);
      tile[ty][nb + 0] = u.x; tile[ty][nb + 1] = u.y;
      tile[ty][nb + 2] = u.z; tile[ty][nb + 3] = u.w;
    } else {
      float4 f = *(const float4*)((const float*)W + (size_t)k * N + n0 + nb);
      tile[ty][nb + 0] = f2bf(f.x); tile[ty][nb + 1] = f2bf(f.y);
      tile[ty][nb + 2] = f2bf(f.z); tile[ty][nb + 3] = f2bf(f.w);
    }
  }
  __syncthreads();
  {
    int n = ty, kk = tx * 4;
    ushortx4 o;
    o.x = tile[kk + 0][n]; o.y = tile[kk + 1][n];
    o.z = tile[kk + 2][n]; o.w = tile[kk + 3][n];
    *(ushortx4*)(WT + (size_t)(rowOff + n0 + n) * 4096 + k0 + kk) = o;
  }
}

// ---------------- bf16 MFMA GEMM: C[M,N] = A[M,K] * BT[N,K]^T ----------------
__device__ inline void gload16(const unsigned short* g, unsigned short* lds) {
  __builtin_amdgcn_global_load_lds(
      (const __attribute__((address_space(1))) unsigned int*)g,
      (__attribute__((address_space(3))) unsigned int*)lds, 16, 0, 0);
}

template <int OUTMODE>  // 0: bf16 out; 1: flag-selected (bf16 if flag else fp32)
__global__ __launch_bounds__(256) void gemm_bt(const unsigned short* __restrict__ A,
                                               const unsigned short* __restrict__ BT,
                                               void* __restrict__ C, int M, int N, int K,
                                               const int* __restrict__ flag) {
  __shared__ __attribute__((aligned(16))) unsigned short As[128 * 32];
  __shared__ __attribute__((aligned(16))) unsigned short Bs[128 * 32];
  int tid = threadIdx.x;
  int w = tid >> 6, l = tid & 63;
  int wm = w >> 1, wn = w & 1;
  // XCD-aware swizzle: dispatch order f -> XCD f%8 (heuristic). Give each XCD a
  // contiguous band of M tile-rows walked row-major: A-row tile (1 MB) stays hot
  // in that XCD's L2; all XCDs touch the same B tile simultaneously (LLC-shared).
  int gx = gridDim.x, gy = gridDim.y;
  int f = blockIdx.y * gx + blockIdx.x;
  int band = gy >> 3;
  int loc = f >> 3;
  int xcd = f & 7;
  int bx = loc % gx;
  int by = xcd * band + loc / gx;
  int m0 = by * 128, n0 = bx * 128;
  int lane15 = l & 15, quad = l >> 4;
  int rA = w * 16 + (l >> 2);
  int c8 = (l & 3) * 8;
  const unsigned short* Ab = A + (size_t)m0 * K;
  const unsigned short* Bb = BT + (size_t)n0 * K;
  floatx4 acc[4][4] = {};

  for (int k0 = 0; k0 < K; k0 += 32) {
#pragma unroll
    for (int p = 0; p < 2; ++p) {
      gload16(Ab + (size_t)(p * 64 + rA) * K + k0 + c8, &As[(p * 64 + w * 16) * 32]);
      gload16(Bb + (size_t)(p * 64 + rA) * K + k0 + c8, &Bs[(p * 64 + w * 16) * 32]);
    }
    __syncthreads();
    const unsigned short* pa = As + (wm * 64 + lane15) * 32 + quad * 8;
    const unsigned short* pb = Bs + (wn * 64 + lane15) * 32 + quad * 8;
    short8 af[4], bfr[4];
#pragma unroll
    for (int i = 0; i < 4; ++i) {
      af[i] = *(const short8*)(pa + i * 512);
      bfr[i] = *(const short8*)(pb + i * 512);
    }
#pragma unroll
    for (int mi = 0; mi < 4; ++mi)
#pragma unroll
      for (int ni = 0; ni < 4; ++ni)
        acc[mi][ni] = __builtin_amdgcn_mfma_f32_16x16x32_bf16(af[mi], bfr[ni], acc[mi][ni], 0, 0, 0);
    __syncthreads();
  }

  bool obf = true;
  if (OUTMODE == 1) obf = (flag[0] != 0);
#pragma unroll
  for (int mi = 0; mi < 4; ++mi) {
    int rbase = m0 + wm * 64 + mi * 16 + quad * 4;
#pragma unroll
    for (int ni = 0; ni < 4; ++ni) {
      int col = n0 + wn * 64 + ni * 16 + lane15;
#pragma unroll
      for (int rr = 0; rr < 4; ++rr) {
        float v = acc[mi][ni][rr];
        size_t idx = (size_t)(rbase + rr) * N + col;
        if (OUTMODE == 0 || obf)
          ((unsigned short*)C)[idx] = f2bf(v);
        else
          ((float*)C)[idx] = v;
      }
    }
  }
}

// ---------------- fused head-softmax + PV per token (RoPE provably cancels) ----------------
// scores = (RoPE q)·(RoPE k) at SAME position = q·k (rotation preserves inner
// products; cos/sin pair structure is an exact 2D rotation per (d, d+64) pair).
// V is unrotated, so the entire RoPE stage is a no-op for the output.
__global__ __launch_bounds__(256) void attn_kernel(const unsigned short* __restrict__ QKV,
                                                   unsigned short* __restrict__ AO) {
  __shared__ __attribute__((aligned(16))) float qf[32 * 132];
  __shared__ __attribute__((aligned(16))) float kf[8 * 132];
  __shared__ __attribute__((aligned(16))) float vf[8 * 132];
  __shared__ float P[256];
  int r = blockIdx.x;
  int t = threadIdx.x;
  const unsigned short* row = QKV + (size_t)r * 6144;

  // Load 6144 bf16 = 768 chunks of 8; 3 chunks/thread, 16B coalesced loads.
#pragma unroll
  for (int c = 0; c < 3; ++c) {
    int chunk = c * 256 + t;
    int e = chunk * 8;
    ushortx4 u0 = *(const ushortx4*)(row + e);
    ushortx4 u1 = *(const ushortx4*)(row + e + 4);
    float* dst;
    if (e < 4096) {
      dst = qf + (e >> 7) * 132 + (e & 127);
    } else if (e < 5120) {
      int e2 = e - 4096;
      dst = kf + (e2 >> 7) * 132 + (e2 & 127);
    } else {
      int e2 = e - 5120;
      dst = vf + (e2 >> 7) * 132 + (e2 & 127);
    }
    float4 w0, w1;
    w0.x = bf2f(u0.x); w0.y = bf2f(u0.y); w0.z = bf2f(u0.z); w0.w = bf2f(u0.w);
    w1.x = bf2f(u1.x); w1.y = bf2f(u1.y); w1.z = bf2f(u1.z); w1.w = bf2f(u1.w);
    *(float4*)dst = w0;
    *(float4*)(dst + 4) = w1;
  }
  __syncthreads();

  // scores: thread t -> (h = t>>3, j = t&7)
  int h = t >> 3, j = t & 7;
  const float4* q4 = (const float4*)(qf + h * 132);
  const float4* k4 = (const float4*)(kf + j * 132);
  float s = 0.f;
#pragma unroll
  for (int d4 = 0; d4 < 32; ++d4) {
    float4 a = q4[d4], b = k4[d4];
    s += a.x * b.x + a.y * b.y + a.z * b.z + a.w * b.w;
  }
  s *= 0.08838834764831845f;  // 1/sqrt(128)
  float mx = s;
  mx = fmaxf(mx, __shfl_xor(mx, 1));
  mx = fmaxf(mx, __shfl_xor(mx, 2));
  mx = fmaxf(mx, __shfl_xor(mx, 4));
  float ex = expf(s - mx);
  float sm = ex;
  sm += __shfl_xor(sm, 1);
  sm += __shfl_xor(sm, 2);
  sm += __shfl_xor(sm, 4);
  P[t] = ex / sm;
  __syncthreads();

  // out[h][d0..d0+16) = sum_j P[h][j] * v[j][d]; rotate c-chunk per lane to
  // break the d0%32 bank aliasing down to free 2-way.
  int d0 = (t & 7) * 16;
  int rot = t & 3;
  float o[16];
#pragma unroll
  for (int c = 0; c < 16; ++c) o[c] = 0.f;
#pragma unroll
  for (int j2 = 0; j2 < 8; ++j2) {
    float pj = P[h * 8 + j2];
    const float* vbase = vf + j2 * 132 + d0;
#pragma unroll
    for (int c = 0; c < 4; ++c) {
      int cc = (c + rot) & 3;
      float4 x = *(const float4*)(vbase + cc * 4);
      o[cc * 4 + 0] += pj * x.x;
      o[cc * 4 + 1] += pj * x.y;
      o[cc * 4 + 2] += pj * x.z;
      o[cc * 4 + 3] += pj * x.w;
    }
  }
  unsigned short* outp = AO + (size_t)r * 4096 + h * 128 + d0;
#pragma unroll
  for (int c = 0; c < 4; ++c) {
    ushortx4 ov;
    ov.x = f2bf(o[c * 4 + 0]);
    ov.y = f2bf(o[c * 4 + 1]);
    ov.z = f2bf(o[c * 4 + 2]);
    ov.w = f2bf(o[c * 4 + 3]);
    *(ushortx4*)(outp + c * 4) = ov;
  }
}

extern "C" void kernel_launch(void* const* d_in, const int* in_sizes, int n_in,
                              void* d_out, int out_size, void* d_ws, size_t ws_size,
                              hipStream_t stream) {
  (void)in_sizes; (void)n_in; (void)out_size; (void)ws_size;
  const void* X  = d_in[0];
  const void* Wq = d_in[1];
  const void* Wk = d_in[2];
  const void* Wv = d_in[3];
  const void* Wo = d_in[4];
  char* ws = (char*)d_ws;
  unsigned short* Xb   = (unsigned short*)(ws);                 // 8192x4096 bf16
  unsigned short* WT   = (unsigned short*)(ws + 67108864);      // 6144x4096 bf16 (Wq|Wk|Wv)^T
  unsigned short* WoT  = (unsigned short*)(ws + 117440512);     // 4096x4096 bf16
  unsigned short* QKVb = (unsigned short*)(ws + 150994944);     // 8192x6144 bf16
  int* flag            = (int*)(ws + 251658240);
  unsigned short* AO = Xb;  // alias: Xb dead after gemm1

  probe_kernel<<<1, 256, 0, stream>>>((const unsigned short*)X, flag);
  cast_any<<<16384, 256, 0, stream>>>(X, Xb, flag, 33554432);
  transpose_cast<<<dim3(128, 128), 256, 0, stream>>>(Wq, WT, flag, 4096, 0);
  transpose_cast<<<dim3(32, 128), 256, 0, stream>>>(Wk, WT, flag, 1024, 4096);
  transpose_cast<<<dim3(32, 128), 256, 0, stream>>>(Wv, WT, flag, 1024, 5120);
  transpose_cast<<<dim3(128, 128), 256, 0, stream>>>(Wo, WoT, flag, 4096, 0);
  gemm_bt<0><<<dim3(48, 64), 256, 0, stream>>>(Xb, WT, QKVb, 8192, 6144, 4096, flag);
  attn_kernel<<<8192, 256, 0, stream>>>(QKVb, AO);
  gemm_bt<1><<<dim3(32, 64), 256, 0, stream>>>(AO, WoT, d_out, 8192, 4096, 4096, flag);
}